// Round 2
// baseline (390.311 us; speedup 1.0000x reference)
//
#include <hip/hip_runtime.h>
#include <hip/hip_bf16.h>

#define Bdim 64
#define Tdim 96
#define Pdim 256
#define Hdim 128
#define Gdim 512   // 4*H
#define Odim 24
#define BH   32    // batches per stream (two streams per block)

typedef _Float16 f16x8 __attribute__((ext_vector_type(8)));
typedef float    f32x16 __attribute__((ext_vector_type(16)));
typedef float    f32x2  __attribute__((ext_vector_type(2)));

union H8 { uint4 u4; unsigned short s[8]; _Float16 h[8]; f16x8 v; };
union HS { _Float16 h; unsigned short s; };

__device__ __forceinline__ float exp2_fast(float x) {
#if __has_builtin(__builtin_amdgcn_exp2f)
    return __builtin_amdgcn_exp2f(x);
#else
    return __expf(x * 0.6931471805599453f);
#endif
}

// One block per point p (grid=256, 1024 threads = 16 waves). Wave w owns r' rows
// [32w,32w+32); r' = 4*k+gate (i,f,g,o): regs 4q..4q+3 of a lane = 4 gates of one
// (b,k). B=64 in two 32-batch streams.
//
// THIS ROUND: single barrier per timestep (was 2). Within a step, all LDS reads
// hit buffer P and all epilogue writes hit buffer P^1 -> no intra-step hazard.
// Schedule: gemm_s0(t); {gemm_s1(t) || ep_s0(t)}; ep_s1(t); barrier.
// 96 barriers instead of 192; two independent 9-MFMA chains per region for ILP.
//
// h storage: row b = 256 B = 16 chunks of 16 B, chunk c stored at position
// c ^ (b & 15)  (XOR swizzle, no padding). The gemm read of chunk c = 2ks+hi by
// lane b=l31 is ONE aligned ds_read_b128 at dword offset 64*l31 + 4*(c^(l31&15));
// pos mod 8 is an XOR-bijection of l31 -> exactly 8 lanes per 4-bank group per
// wave64 = perfectly balanced banks, 8 cy/read.
//
// Math: log2e-prescaled weights (2log2e for g), gx fused as 9th MFMA K-step,
// scaled-domain cell state, paired-rcp epilogue (6 trans per (b,k)).
__global__ __launch_bounds__(1024, 4)
void lstm_fused(const float* __restrict__ x,
                const float* __restrict__ W_ih,
                const float* __restrict__ W_hh,
                const float* __restrict__ b_ih,
                const float* __restrict__ b_hh,
                const float* __restrict__ W_fc,
                const float* __restrict__ b_fc,
                float* __restrict__ out)
{
    __shared__ unsigned short hb0[2][BH * Hdim];  // stream0 h, double-buffered, swizzled
    __shared__ unsigned short hb1[2][BH * Hdim];  // stream1 h, double-buffered, swizzled

    const int p   = blockIdx.x;
    const int tid = threadIdx.x;
    const int w   = tid >> 6;    // wave 0..15
    const int l31 = tid & 31;
    const int hi  = (tid >> 5) & 1;

    const float L1 = 1.4426950408889634f;  // log2(e)
    const float L2 = 2.0f * L1;

    for (int i = tid; i < 2 * BH * Hdim; i += 1024) ((unsigned short*)hb0)[i] = 0;
    for (int i = tid; i < 2 * BH * Hdim; i += 1024) ((unsigned short*)hb1)[i] = 0;

    // ---- preload shared A fragments (time-invariant): W_hh rows + gx row ----
    f16x8 afr[9];
    {
        const int rp   = w * 32 + l31;                // r'
        const int orow = ((rp & 3) << 7) | (rp >> 2); // gate*128 + k
        const float sc = ((rp & 3) == 2) ? L2 : L1;   // g gate: 2*log2e
        const float* rowp = W_hh + (size_t)p * Gdim * Hdim + (size_t)orow * Hdim;
        #pragma unroll
        for (int ks = 0; ks < 8; ++ks) {
            int k0 = ks * 16 + hi * 8;
            float4 va = *(const float4*)(rowp + k0);
            float4 vb = *(const float4*)(rowp + k0 + 4);
            H8 u;
            u.h[0] = (_Float16)(sc * va.x); u.h[1] = (_Float16)(sc * va.y);
            u.h[2] = (_Float16)(sc * va.z); u.h[3] = (_Float16)(sc * va.w);
            u.h[4] = (_Float16)(sc * vb.x); u.h[5] = (_Float16)(sc * vb.y);
            u.h[6] = (_Float16)(sc * vb.z); u.h[7] = (_Float16)(sc * vb.w);
            afr[ks] = u.v;
        }
        H8 u9;
        #pragma unroll
        for (int j = 0; j < 8; ++j) u9.s[j] = 0;
        if (hi == 0) {
            u9.h[0] = (_Float16)(sc * W_ih[(size_t)p * Gdim + orow]);
            u9.h[1] = (_Float16)(sc * (b_ih[(size_t)p * Gdim + orow] +
                                       b_hh[(size_t)p * Gdim + orow]));
        }
        afr[8] = u9.v;
    }

    // swizzled ds_read_b128: row l31, chunk c = 2ks+hi
    auto ldh = [&](const unsigned short* hb, int ks) -> H8 {
        H8 r;
        int c   = ks * 2 + hi;
        int off = (l31 << 8) + ((c ^ (l31 & 15)) << 4);   // bytes
        r.u4 = *(const uint4*)((const char*)hb + off);
        return r;
    };

    // epilogue for q-pair (q=2j, 2j+1) of one stream: acc -> new c, h -> wb (swizzled)
    auto ep_pair = [&](const f32x16& a, int j, f32x2* cr, unsigned short* wb) {
        f32x2 yi = {a[8 * j + 0], a[8 * j + 4]};
        f32x2 yf = {a[8 * j + 1], a[8 * j + 5]};
        f32x2 yg = {a[8 * j + 2], a[8 * j + 6]};   // prescaled by 2*log2e
        f32x2 yo = {a[8 * j + 3], a[8 * j + 7]};
        f32x2 Ef = {exp2_fast(-yf.x), exp2_fast(-yf.y)};
        f32x2 Ei = {exp2_fast(-yi.x), exp2_fast(-yi.y)};
        f32x2 Eg = {exp2_fast(yg.x),  exp2_fast(yg.y)};
        f32x2 t1 = Ef + 1.0f;
        f32x2 t2 = Ei + 1.0f;
        f32x2 t3 = Eg + 1.0f;
        f32x2 t4 = Eg - 1.0f;
        f32x2 den = (t1 * t2) * t3;
        f32x2 num = (cr[j] * t2) * t3 + (L2 * t4) * t1;
        float D = den.x * den.y;
        float r = __builtin_amdgcn_rcpf(D);
        f32x2 inv = {r * den.y, r * den.x};
        f32x2 cn  = num * inv;
        cn.x = __builtin_amdgcn_fmed3f(cn.x, -30.0f, 30.0f);
        cn.y = __builtin_amdgcn_fmed3f(cn.y, -30.0f, 30.0f);
        cr[j] = cn;
        f32x2 Eo = {exp2_fast(-yo.x), exp2_fast(-yo.y)};
        f32x2 Ec = {exp2_fast(cn.x),  exp2_fast(cn.y)};
        f32x2 d2 = (Eo + 1.0f) * (Ec + 1.0f);
        float D2 = d2.x * d2.y;
        float r2 = __builtin_amdgcn_rcpf(D2);
        f32x2 j2 = {r2 * d2.y, r2 * d2.x};
        f32x2 hv = (Ec - 1.0f) * j2;
        HS ha; ha.h = (_Float16)hv.x;
        HS hc; hc.h = (_Float16)hv.y;
        // k = w*8 + 4j + hi (+2); chunk = w -> swizzled pos = w ^ (l31&15)
        int base = (l31 << 7) + ((w ^ (l31 & 15)) << 3) + 4 * j + hi;
        wb[base]     = ha.s;   // q = 2j
        wb[base + 2] = hc.s;   // q = 2j+1
    };

    // one fragment of a step: gemm of one stream (rb -> acc, in place) interleaved
    // with the epilogue of the other stream (ar -> wb). doGemm/doEp compile-time
    // constant at each call site (inlined lambda).
    auto phase = [&](const unsigned short* rb, unsigned short* wb,
                     f32x16& acc, const f32x16& ar, f32x2* cr, float xv,
                     bool doGemm, bool doEp) {
        if (doGemm) {
            H8 f0 = ldh(rb, 0), f1 = ldh(rb, 1);
            H8 f2 = ldh(rb, 2), f3 = ldh(rb, 3);
            f32x16 z;
            #pragma unroll
            for (int j = 0; j < 16; ++j) z[j] = 0.f;
            acc = __builtin_amdgcn_mfma_f32_32x32x16_f16(afr[0], f0.v, z, 0, 0, 0);
            acc = __builtin_amdgcn_mfma_f32_32x32x16_f16(afr[1], f1.v, acc, 0, 0, 0);
            if (doEp) ep_pair(ar, 0, cr, wb);
            H8 f4 = ldh(rb, 4), f5 = ldh(rb, 5);
            acc = __builtin_amdgcn_mfma_f32_32x32x16_f16(afr[2], f2.v, acc, 0, 0, 0);
            acc = __builtin_amdgcn_mfma_f32_32x32x16_f16(afr[3], f3.v, acc, 0, 0, 0);
            if (doEp) ep_pair(ar, 1, cr, wb);
            H8 f6 = ldh(rb, 6), f7 = ldh(rb, 7);
            acc = __builtin_amdgcn_mfma_f32_32x32x16_f16(afr[4], f4.v, acc, 0, 0, 0);
            acc = __builtin_amdgcn_mfma_f32_32x32x16_f16(afr[5], f5.v, acc, 0, 0, 0);
            acc = __builtin_amdgcn_mfma_f32_32x32x16_f16(afr[6], f6.v, acc, 0, 0, 0);
            acc = __builtin_amdgcn_mfma_f32_32x32x16_f16(afr[7], f7.v, acc, 0, 0, 0);
            H8 bg;
            #pragma unroll
            for (int j = 0; j < 8; ++j) bg.s[j] = 0;
            if (hi == 0) { bg.h[0] = (_Float16)xv; bg.h[1] = (_Float16)1.0f; }
            acc = __builtin_amdgcn_mfma_f32_32x32x16_f16(afr[8], bg.v, acc, 0, 0, 0);
        } else if (doEp) {
            ep_pair(ar, 0, cr, wb);
            ep_pair(ar, 1, cr, wb);
        }
    };

    f32x2 cre0[2] = {f32x2{0.f, 0.f}, f32x2{0.f, 0.f}};
    f32x2 cre1[2] = {f32x2{0.f, 0.f}, f32x2{0.f, 0.f}};
    f32x16 acc0, acc1;
    #pragma unroll
    for (int j = 0; j < 16; ++j) { acc0[j] = 0.f; acc1[j] = 0.f; }

    const float* xp0 = x + (size_t)((0 * BH + l31) * Tdim) * Pdim + p;
    const float* xp1 = x + (size_t)((1 * BH + l31) * Tdim) * Pdim + p;
    float xv0 = xp0[0];
    float xv1 = xp1[0];

    __syncthreads();

    // one region per step, ONE barrier per step.
    // region t: all reads from buffer P, all writes to buffer P^1.
    for (int t = 0; t < Tdim; ++t) {
        const int P  = t & 1;
        const int tn = (t + 1 < Tdim) ? (t + 1) : t;
        float xn0 = xp0[(size_t)tn * Pdim];   // prefetch x for t+1
        float xn1 = xp1[(size_t)tn * Pdim];

        // gemm_s0(t): hb0[P] -> acc0 (no ep interleave)
        phase(hb0[P], hb0[P ^ 1], acc0, acc1, cre1, xv0, true, false);
        // gemm_s1(t) || ep_s0(t): hb1[P] -> acc1 ; acc0 -> hb0[P^1]
        phase(hb1[P], hb0[P ^ 1], acc1, acc0, cre0, xv1, true, true);
        // ep_s1(t): acc1 -> hb1[P^1]
        phase(hb1[P], hb1[P ^ 1], acc1, acc1, cre1, 0.f, false, true);

        __syncthreads();
        xv0 = xn0;
        xv1 = xn1;
    }
    // final h (t=95 writes buffer (95&1)^1 = 0): stream0 in hb0[0], stream1 in hb1[0]

    // ---- FC: out[b][o][p] = sum_k W_fc[p][o][k]*h[b][k] + b_fc[p][o] ----
    const float* wfc = W_fc + (size_t)p * Odim * Hdim;
    const float* bfc = b_fc + (size_t)p * Odim;
    for (int i = tid; i < Bdim * Odim; i += 1024) {
        int o = i % Odim;
        int b = i / Odim;            // global batch 0..63
        int bl = (b < BH) ? b : (b - BH);
        const unsigned short* hr = (b < BH) ? (hb0[0] + (bl << 7))
                                            : (hb1[0] + (bl << 7));
        float s = bfc[o];
        const float* wr = wfc + o * Hdim;
        #pragma unroll 8
        for (int k2 = 0; k2 < Hdim; ++k2) {
            int idx = (((k2 >> 3) ^ (bl & 15)) << 3) + (k2 & 7);   // unswizzle
            HS s2; s2.s = hr[idx];
            s = __builtin_fmaf(wr[k2], (float)s2.h, s);
        }
        out[(size_t)b * Odim * Pdim + (size_t)o * Pdim + p] = s;
    }
}

extern "C" void kernel_launch(void* const* d_in, const int* in_sizes, int n_in,
                              void* d_out, int out_size, void* d_ws, size_t ws_size,
                              hipStream_t stream) {
    const float* x    = (const float*)d_in[0];
    const float* W_ih = (const float*)d_in[1];
    const float* W_hh = (const float*)d_in[2];
    const float* b_ih = (const float*)d_in[3];
    const float* b_hh = (const float*)d_in[4];
    const float* W_fc = (const float*)d_in[5];
    const float* b_fc = (const float*)d_in[6];
    float* out = (float*)d_out;

    lstm_fused<<<dim3(Pdim), dim3(1024), 0, stream>>>(x, W_ih, W_hh, b_ih, b_hh, W_fc, b_fc, out);
}